// Round 6
// baseline (179.924 us; speedup 1.0000x reference)
//
#include <hip/hip_runtime.h>
#include <math.h>

#define T_ 4096
#define C_ 768
#define H_ 12
#define D_ 64
#define TC_ ((size_t)T_ * C_)
#define CC_ ((size_t)C_ * C_)

typedef __attribute__((ext_vector_type(8))) __bf16 bf16x8;
typedef __attribute__((ext_vector_type(4))) __bf16 bf16x4;
typedef __attribute__((ext_vector_type(4))) float f32x4;
typedef __attribute__((ext_vector_type(16))) float f32x16;
typedef __attribute__((ext_vector_type(8))) unsigned short u16x8;

static __device__ __forceinline__ float fast_exp2(float x) {
#if __has_builtin(__builtin_amdgcn_exp2f)
    return __builtin_amdgcn_exp2f(x);
#else
    return exp2f(x);
#endif
}

// pack two f32 -> u32 of 2 bf16 (RNE via hardware cvt; compiler emits cvt_pk)
static __device__ __forceinline__ unsigned pack2(float a, float b) {
    unsigned short lo = __builtin_bit_cast(unsigned short, (__bf16)a);
    unsigned short hi = __builtin_bit_cast(unsigned short, (__bf16)b);
    return (unsigned)lo | ((unsigned)hi << 16);
}

// global (16B per lane) -> LDS direct, wave-uniform LDS base + lane*16
static __device__ __forceinline__ void gload16(const void* g, void* l) {
    __builtin_amdgcn_global_load_lds(
        (const __attribute__((address_space(1))) unsigned int*)g,
        (__attribute__((address_space(3))) unsigned int*)l, 16, 0, 0);
}

// ---------------------------------------------------------------------------
// fp32 -> bf16 convert (RNE), n4 = n/4
// ---------------------------------------------------------------------------
__global__ void f2b_kernel(const float* __restrict__ in,
                           unsigned short* __restrict__ out, int n4) {
    int i = blockIdx.x * blockDim.x + threadIdx.x;
    const int stride = gridDim.x * blockDim.x;
    for (; i < n4; i += stride) {
        float4 v = ((const float4*)in)[i];
        bf16x4 o = { (__bf16)v.x, (__bf16)v.y, (__bf16)v.z, (__bf16)v.w };
        *(bf16x4*)&out[(size_t)i * 4] = o;
    }
}

// ---------------------------------------------------------------------------
// m97-style 128x128 GEMM core (verified round 3)
// ---------------------------------------------------------------------------
#define BM 128
#define BN 128
#define BKG 64

struct GemmRegs {
    const unsigned short* ag[4];
    const unsigned short* wg[4];
    unsigned short* la[4];
    unsigned short* lw[4];
    int lq, lg, wr, wc;
};

static __device__ __forceinline__ void gemm_setup(
    GemmRegs& R, const unsigned short* A, const unsigned short* W,
    unsigned short* Asm, unsigned short* Bsm, int bm, int bn, int K)
{
    const int tid = threadIdx.x;
    const int wave = tid >> 6, lane = tid & 63;
    R.lq = lane & 15; R.lg = lane >> 4;
    R.wr = wave >> 1; R.wc = wave & 1;
#pragma unroll
    for (int i = 0; i < 4; ++i) {
        const int flat = wave * 256 + i * 64 + lane;   // 0..1023
        const int row = flat >> 3, cb = flat & 7;
        R.ag[i] = A + (size_t)(bm + row) * K + cb * 8;
        R.wg[i] = W + (size_t)(bn + row) * K + cb * 8;
        R.la[i] = Asm + (wave * 4 + i) * 512;
        R.lw[i] = Bsm + (wave * 4 + i) * 512;
    }
}

static __device__ __forceinline__ void gemm_loop(
    GemmRegs& R, unsigned short* Asm, unsigned short* Bsm, int K, f32x4 acc[4][4])
{
    for (int kb = 0; kb < K; kb += BKG) {
        __syncthreads();   // previous tile fully consumed
#pragma unroll
        for (int i = 0; i < 4; ++i) {
            gload16(R.ag[i] + kb, R.la[i]);
            gload16(R.wg[i] + kb, R.lw[i]);
        }
        __syncthreads();   // staged
        __builtin_amdgcn_s_setprio(1);
#pragma unroll
        for (int ks = 0; ks < 2; ++ks) {
            bf16x8 af[4], wf[4];
#pragma unroll
            for (int m = 0; m < 4; ++m)
                af[m] = *(const bf16x8*)&Asm[(R.wr * 64 + m * 16 + R.lq) * BKG + ks * 32 + R.lg * 8];
#pragma unroll
            for (int n = 0; n < 4; ++n)
                wf[n] = *(const bf16x8*)&Bsm[(R.wc * 64 + n * 16 + R.lq) * BKG + ks * 32 + R.lg * 8];
#pragma unroll
            for (int m = 0; m < 4; ++m)
#pragma unroll
                for (int n = 0; n < 4; ++n)
                    acc[m][n] = __builtin_amdgcn_mfma_f32_16x16x32_bf16(af[m], wf[n], acc[m][n], 0, 0, 0);
        }
        __builtin_amdgcn_s_setprio(0);
    }
}

// Fused QKV projection: z selects {Q (scaled), K, V (head-transposed)}
__global__ __launch_bounds__(256) void qkv128(
    const unsigned short* __restrict__ xb,
    const unsigned short* __restrict__ Wqb, const unsigned short* __restrict__ Wkb,
    const unsigned short* __restrict__ Wvb,
    const float* __restrict__ bq, const float* __restrict__ bk, const float* __restrict__ bv,
    unsigned short* __restrict__ Qb, unsigned short* __restrict__ Kb,
    unsigned short* __restrict__ Vtb)
{
    __shared__ unsigned short Asm[BM * BKG];
    __shared__ unsigned short Bsm[BN * BKG];
    const int z = blockIdx.z;
    const unsigned short* W = (z == 0) ? Wqb : (z == 1) ? Wkb : Wvb;
    const float* bias = (z == 0) ? bq : (z == 1) ? bk : bv;
    const int bm = blockIdx.x * BM, bn = blockIdx.y * BN;

    GemmRegs R;
    gemm_setup(R, xb, W, Asm, Bsm, bm, bn, C_);
    f32x4 acc[4][4] = {};
    gemm_loop(R, Asm, Bsm, C_, acc);

    // 0.125 * log2(e): QK^T scores land in log2 domain
    const float sc = (z == 0) ? 0.18033688011112042f : 1.0f;
#pragma unroll
    for (int mt = 0; mt < 4; ++mt) {
        const int m0 = bm + R.wr * 64 + mt * 16 + R.lg * 4;
#pragma unroll
        for (int nt = 0; nt < 4; ++nt) {
            const int n = bn + R.wc * 64 + nt * 16 + R.lq;
            const float b = bias[n];
            if (z == 2) {
                bf16x4 o = { (__bf16)(acc[mt][nt][0] + b), (__bf16)(acc[mt][nt][1] + b),
                             (__bf16)(acc[mt][nt][2] + b), (__bf16)(acc[mt][nt][3] + b) };
                *(bf16x4*)&Vtb[(size_t)n * T_ + m0] = o;
            } else {
                unsigned short* Y = (z == 0) ? Qb : Kb;
#pragma unroll
                for (int r = 0; r < 4; ++r)
                    Y[(size_t)(m0 + r) * C_ + n] =
                        __builtin_bit_cast(unsigned short, (__bf16)((acc[mt][nt][r] + b) * sc));
            }
        }
    }
}

// Output projection: fp32 out + bias
__global__ __launch_bounds__(256) void out128(
    const unsigned short* __restrict__ ctxb, const unsigned short* __restrict__ Wob,
    const float* __restrict__ bo, float* __restrict__ out)
{
    __shared__ unsigned short Asm[BM * BKG];
    __shared__ unsigned short Bsm[BN * BKG];
    const int bm = blockIdx.x * BM, bn = blockIdx.y * BN;

    GemmRegs R;
    gemm_setup(R, ctxb, Wob, Asm, Bsm, bm, bn, C_);
    f32x4 acc[4][4] = {};
    gemm_loop(R, Asm, Bsm, C_, acc);

#pragma unroll
    for (int mt = 0; mt < 4; ++mt) {
        const int m0 = bm + R.wr * 64 + mt * 16 + R.lg * 4;
#pragma unroll
        for (int nt = 0; nt < 4; ++nt) {
            const int n = bn + R.wc * 64 + nt * 16 + R.lq;
            const float b = bo[n];
#pragma unroll
            for (int r = 0; r < 4; ++r)
                out[(size_t)(m0 + r) * C_ + n] = acc[mt][nt][r] + b;
        }
    }
}

// ---------------------------------------------------------------------------
// Flash attention: 32x32x16 MFMA, wave owns 32 q-rows. Block = 2 waves = 64 q.
// Swapped QK^T (S^T = K·Q^T): lane l holds (with partner l^32) all 64 scores
// of q-row (l&31). Cross-half reduce via __shfl_xor(...,32) (verified r2/r3).
// P staged through per-wave padded LDS [32][72] (verified same-wave pattern,
// round 3) — NO inline asm anywhere.
// K/V LDS tiles XOR-swizzled: LDS[row][c] = G[row][c ^ ((row&7)<<4)] via
// pre-swizzled SOURCE addrs (linear global_load_lds dest); reads apply the
// same involution to the full column. Double-buffered, one barrier per tile.
// Q pre-scaled by 0.125*log2(e) -> exp2 softmax, defer-max (T13).
// ---------------------------------------------------------------------------
#define NTI (T_ / 64)
#define LDP 72

__global__ __launch_bounds__(128) void attn32(
    const unsigned short* __restrict__ Qb, const unsigned short* __restrict__ Kb,
    const unsigned short* __restrict__ Vtb, unsigned short* __restrict__ ctx)
{
    __shared__ unsigned short Ks[2][64 * 64];
    __shared__ unsigned short Vs[2][64 * 64];
    __shared__ unsigned short Ps[2][32 * LDP];

    const int tid = threadIdx.x;
    const int wave = tid >> 6, lane = tid & 63;
    const int lq = lane & 31, hi = lane >> 5;

    // bijective XCD swizzle: 768 blocks -> 96 contiguous per XCD (~1.5 heads)
    const int bid = blockIdx.x;
    const int sw = (bid & 7) * 96 + (bid >> 3);
    const int h = sw / 64, qt = sw % 64;
    const int q0 = qt * 64 + wave * 32;

    // swizzled LDS read offsets (bytes): row=lq (+32 via +4096), col chunk per ks
    const int swz = (lq & 7) << 4;
    int rof[4];
#pragma unroll
    for (int ks = 0; ks < 4; ++ks)
        rof[ks] = lq * 128 + ((hi * 16 + ks * 32) ^ swz);

    // Q B-frags: lane holds Q[q0+lq][ks*16 + hi*8 + i]
    bf16x8 qf[4];
    {
        const unsigned short* qp = Qb + (size_t)(q0 + lq) * C_ + h * D_ + hi * 8;
#pragma unroll
        for (int ks = 0; ks < 4; ++ks) qf[ks] = *(const bf16x8*)(qp + ks * 16);
    }

    // staging: slot s = (wave*4+j)*64 + lane; row = s>>3; src col pre-swizzled
    const char* gk[4];
    const char* gv[4];
#pragma unroll
    for (int j = 0; j < 4; ++j) {
        const int s = (wave * 4 + j) * 64 + lane;
        const int row = s >> 3;
        const int cp = ((s & 7) * 16) ^ ((row & 7) << 4);
        gk[j] = (const char*)Kb + (size_t)row * (C_ * 2) + h * (D_ * 2) + cp;
        gv[j] = (const char*)Vtb + (size_t)(h * D_ + row) * (T_ * 2) + cp;
    }

    f32x16 oacc0 = {}, oacc1 = {};
    float mrun = -3.4e38f, lrun = 0.f;

    // prologue: stage tile 0 into buf 0
#pragma unroll
    for (int j = 0; j < 4; ++j) {
        gload16(gk[j], &Ks[0][(wave * 4 + j) * 512]);
        gload16(gv[j], &Vs[0][(wave * 4 + j) * 512]);
    }
    __syncthreads();

    for (int it = 0; it < NTI; ++it) {
        const int cur = it & 1;
        // issue next tile's loads into the other buffer (hidden by compute)
        if (it + 1 < NTI) {
            const size_t ko = (size_t)(it + 1) * 64 * C_ * 2;
            const size_t vo = (size_t)(it + 1) * 128;
#pragma unroll
            for (int j = 0; j < 4; ++j) {
                gload16(gk[j] + ko, &Ks[cur ^ 1][(wave * 4 + j) * 512]);
                gload16(gv[j] + vo, &Vs[cur ^ 1][(wave * 4 + j) * 512]);
            }
        }
        const char* kb = (const char*)&Ks[cur][0];
        const char* vb = (const char*)&Vs[cur][0];

        // S^T = K · Q^T   (s0: kv 0-31 rows, s1: kv 32-63 rows; col = q = lq)
        f32x16 s0 = {}, s1 = {};
        __builtin_amdgcn_s_setprio(1);
#pragma unroll
        for (int ks = 0; ks < 4; ++ks) {
            bf16x8 kf0 = *(const bf16x8*)(kb + rof[ks]);
            bf16x8 kf1 = *(const bf16x8*)(kb + 4096 + rof[ks]);
            s0 = __builtin_amdgcn_mfma_f32_32x32x16_bf16(kf0, qf[ks], s0, 0, 0, 0);
            s1 = __builtin_amdgcn_mfma_f32_32x32x16_bf16(kf1, qf[ks], s1, 0, 0, 0);
        }
        __builtin_amdgcn_s_setprio(0);

        // ---- online softmax (base 2), in-register + shfl cross-half ----
        // reg r of s0: kv = (r&3) + 8*(r>>2) + 4*hi ; s1: +32
        float mx[8];
#pragma unroll
        for (int r = 0; r < 8; ++r)
            mx[r] = fmaxf(fmaxf(s0[r], s0[r + 8]), fmaxf(s1[r], s1[r + 8]));
        mx[0] = fmaxf(mx[0], mx[4]); mx[1] = fmaxf(mx[1], mx[5]);
        mx[2] = fmaxf(mx[2], mx[6]); mx[3] = fmaxf(mx[3], mx[7]);
        float mt = fmaxf(fmaxf(mx[0], mx[1]), fmaxf(mx[2], mx[3]));
        mt = fmaxf(mt, __shfl_xor(mt, 32));
        // defer-max (T13): rescale only when tile max exceeds running max by >8
        if (__any(mt > mrun + 8.0f)) {
            const float mnew = fmaxf(mrun, mt);
            const float fsc = fast_exp2(mrun - mnew);   // first tile: 0
            lrun *= fsc;
#pragma unroll
            for (int r = 0; r < 16; ++r) { oacc0[r] *= fsc; oacc1[r] *= fsc; }
            mrun = mnew;
        }
#pragma unroll
        for (int r = 0; r < 16; ++r) {
            s0[r] = fast_exp2(s0[r] - mrun);
            s1[r] = fast_exp2(s1[r] - mrun);
        }
        {   // row-sum: local tree + cross-half shfl
            float ps[8];
#pragma unroll
            for (int r = 0; r < 8; ++r)
                ps[r] = (s0[r] + s0[r + 8]) + (s1[r] + s1[r + 8]);
            ps[0] += ps[4]; ps[1] += ps[5]; ps[2] += ps[6]; ps[3] += ps[7];
            float pt = (ps[0] + ps[1]) + (ps[2] + ps[3]);
            lrun += pt + __shfl_xor(pt, 32);
        }

        // ---- P (bf16) -> per-wave LDS [q=32][72] (natural [q][kv] layout) ----
        // pairs (r, r+1), r even: kv = (r&3) + 8*(r>>2) + 4*hi, covers kv,kv+1
#pragma unroll
        for (int r = 0; r < 16; r += 2) {
            const int kv = (r & 3) + 8 * (r >> 2) + 4 * hi;
            *(unsigned*)&Ps[wave][lq * LDP + kv]      = pack2(s0[r], s0[r + 1]);
            *(unsigned*)&Ps[wave][lq * LDP + 32 + kv] = pack2(s1[r], s1[r + 1]);
        }
        // same-wave producer/consumer: no barrier (lgkmcnt-ordered)

        // ---- PV: O^T += V^T · P^T ; B-frag = P[lq][ks*16 + hi*8 + i] ----
        __builtin_amdgcn_s_setprio(1);
#pragma unroll
        for (int ks = 0; ks < 4; ++ks) {
            bf16x8 pf = *(const bf16x8*)&Ps[wave][lq * LDP + ks * 16 + hi * 8];
            bf16x8 vf0 = *(const bf16x8*)(vb + rof[ks]);
            bf16x8 vf1 = *(const bf16x8*)(vb + 4096 + rof[ks]);
            oacc0 = __builtin_amdgcn_mfma_f32_32x32x16_bf16(vf0, pf, oacc0, 0, 0, 0);
            oacc1 = __builtin_amdgcn_mfma_f32_32x32x16_bf16(vf1, pf, oacc1, 0, 0, 0);
        }
        __builtin_amdgcn_s_setprio(0);

        __syncthreads();   // next tile staged (vmcnt drained at barrier) + reads done
    }

    // epilogue: oacc reg r -> d = (r&3) + 8*(r>>2) + 4*hi (+32 for oacc1), col q = lq
    const float inv = 1.f / lrun;
    unsigned short* op = ctx + (size_t)(q0 + lq) * C_ + h * D_;
#pragma unroll
    for (int k = 0; k < 4; ++k) {
        bf16x4 o0 = { (__bf16)(oacc0[4 * k + 0] * inv), (__bf16)(oacc0[4 * k + 1] * inv),
                      (__bf16)(oacc0[4 * k + 2] * inv), (__bf16)(oacc0[4 * k + 3] * inv) };
        *(bf16x4*)&op[8 * k + 4 * hi] = o0;
        bf16x4 o1 = { (__bf16)(oacc1[4 * k + 0] * inv), (__bf16)(oacc1[4 * k + 1] * inv),
                      (__bf16)(oacc1[4 * k + 2] * inv), (__bf16)(oacc1[4 * k + 3] * inv) };
        *(bf16x4*)&op[32 + 8 * k + 4 * hi] = o1;
    }
}

// ---------------------------------------------------------------------------
extern "C" void kernel_launch(void* const* d_in, const int* in_sizes, int n_in,
                              void* d_out, int out_size, void* d_ws, size_t ws_size,
                              hipStream_t stream) {
    (void)in_sizes; (void)n_in; (void)out_size; (void)ws_size;
    const float* x  = (const float*)d_in[0];
    const float* Wq = (const float*)d_in[1];
    const float* bq = (const float*)d_in[2];
    const float* Wk = (const float*)d_in[3];
    const float* bk = (const float*)d_in[4];
    const float* Wv = (const float*)d_in[5];
    const float* bv = (const float*)d_in[6];
    const float* Wo = (const float*)d_in[7];
    const float* bo = (const float*)d_in[8];
    float* out = (float*)d_out;

    unsigned short* ws   = (unsigned short*)d_ws;
    unsigned short* xb   = ws;
    unsigned short* Wqb  = xb + TC_;
    unsigned short* Wkb  = Wqb + CC_;
    unsigned short* Wvb  = Wkb + CC_;
    unsigned short* Wob  = Wvb + CC_;
    unsigned short* Qb   = Wob + CC_;
    unsigned short* Kb   = Qb + TC_;
    unsigned short* Vtb  = Kb + TC_;     // [H][D][T]
    unsigned short* ctxb = Vtb + TC_;

    f2b_kernel<<<2048, 256, 0, stream>>>(x, xb, (int)(TC_ / 4));
    f2b_kernel<<<576, 256, 0, stream>>>(Wq, Wqb, (int)(CC_ / 4));
    f2b_kernel<<<576, 256, 0, stream>>>(Wk, Wkb, (int)(CC_ / 4));
    f2b_kernel<<<576, 256, 0, stream>>>(Wv, Wvb, (int)(CC_ / 4));
    f2b_kernel<<<576, 256, 0, stream>>>(Wo, Wob, (int)(CC_ / 4));

    dim3 gq(T_ / BM, C_ / BN, 3);   // 32 x 6 x 3
    qkv128<<<gq, 256, 0, stream>>>(xb, Wqb, Wkb, Wvb, bq, bk, bv, Qb, Kb, Vtb);

    attn32<<<768, 128, 0, stream>>>(Qb, Kb, Vtb, ctxb);

    dim3 go(T_ / BM, C_ / BN);      // 32 x 6
    out128<<<go, 256, 0, stream>>>(ctxb, Wob, bo, out);
}